// Round 5
// baseline (510.756 us; speedup 1.0000x reference)
//
#include <hip/hip_runtime.h>

// ---------------------------------------------------------------------------
// Transformer block (pre-LN attn + FFN), B=16 T=512 D=1024 H=16 HD=64, f32 io.
// bf16 MFMA GEMMs; q/k path uses bf16 hi/lo split (K'=3K GEMM) so the
// UNSCALED K.Q^T scores stay ~f32-accurate.
// GEMM v2.1: 256xBN tile, BK=64, 8 waves, 4-phase/K-tile schedule, counted
// vmcnt (never 0 in loop), raw s_barrier, setprio around MFMA clusters,
// 2-K-tile prefetch, XCD swizzle. Swizzle fix vs v2: chunk XOR uses
// (row>>2)&3 (bank_base = 16*(row&1)+4*chunk -> 2 lanes/bank = free [m136]);
// v2's (row&3) XOR left rows m,m+4 on the same bank (4-way, 9.4M conflicts).
// Attention: fragment-layout flash, 64-s iterations (verified round 3).
// Workspace (~167 MiB, liveness-aliased), x2 lives in d_out.
// ---------------------------------------------------------------------------

#define DEV __device__ __forceinline__

typedef unsigned short u16;
typedef __attribute__((ext_vector_type(8))) __bf16 bf16x8;
typedef __attribute__((ext_vector_type(4))) float f32x4;
typedef __attribute__((ext_vector_type(8))) unsigned short u16x8;

typedef __attribute__((address_space(1))) void as1_void;
typedef __attribute__((address_space(3))) void as3_void;

DEV u16 f2b(float f) {                       // f32 -> bf16 RNE (finite inputs)
  unsigned u = __float_as_uint(f);
  u = (u + 0x7fffu + ((u >> 16) & 1u)) >> 16;
  return (u16)u;
}
DEV float b2f(u16 h) { return __uint_as_float(((unsigned)h) << 16); }

DEV f32x4 mfma16(bf16x8 a, bf16x8 b, f32x4 c) {
  return __builtin_amdgcn_mfma_f32_16x16x32_bf16(a, b, c, 0, 0, 0);
}

// async global->LDS, 16B per lane, dest = uniform base + lane*16
DEV void gload16(const void* g, void* l) {
  __builtin_amdgcn_global_load_lds((as1_void*)(unsigned long long)g,
                                   (as3_void*)(unsigned long long)l,
                                   16u, 0, 0u);
}

#define EPI_BF16 0
#define EPI_RELU 1
#define EPI_RES 2
#define EPI_SPLIT 3
#define EPI_QKFRAG 4
#define EPI_VFRAG 5

// ---------------------------------------------------------------------------
// GEMM v2.1: C[M,N] = A[M,K]*Bt[N,K]^T + bias. BM=256, BK=64, 8 waves.
// Schedule per iteration u (buf cur=u&1), phases p=(kh,mh):
//   p0: read A(kh0,mh0)+B(kh0); stage (u+1).Akh1 -> buf cur^1
//   p1: read A(kh0,mh1);        stage (u+1).Bkh1; vmcnt(NW)
//   p2: read A(kh1,mh0)+B(kh1); stage (u+2).Akh0 -> buf cur
//   p3: read A(kh1,mh1);        stage (u+2).Bkh0; vmcnt(NW)
// NW = 2*(LA+LB); FIFO accounting verified: at each read, that region's
// loads are among the completed prefix. Tail staging clamps kt (dummy
// reloads keep vmcnt counts uniform; targets are dead regions).
// ---------------------------------------------------------------------------
template <int BN, int EPI>
__global__ __launch_bounds__(512, 2) void gemm256(
    const u16* __restrict__ A, int lda, int kdup, const u16* __restrict__ Bt,
    const float* __restrict__ bias, const float* __restrict__ res,
    void* __restrict__ Cout, void* __restrict__ Cout2, int ldc, int N, int K) {
  constexpr int MPW = (BN == 256) ? 128 : 64;  // per-wave m rows
  constexpr int MF = MPW / 16;                 // m-frags per wave (8 or 4)
  constexpr int LA = 2;                        // A gloads/thread/stage-phase
  constexpr int LB = BN / 128;                 // B gloads/thread/stage-phase
  constexpr int NWAIT = 2 * (LA + LB);         // counted vmcnt
  constexpr int ASZ = 256 * 64;                // bytes per (buf,kh) A region
  constexpr int BSZ = BN * 64;
  constexpr int ATOT = 4 * ASZ;
  __shared__ __align__(1024) char lds[4 * ASZ + 4 * BSZ];

  // XCD-contiguous block swizzle (gridDim.x % 8 == 0 by construction)
  const int nwg = (int)gridDim.x;
  const int cpx = nwg >> 3;
  int w = (int)blockIdx.x;
  w = (w & 7) * cpx + (w >> 3);
  const int nbn = N / BN;
  const int bn = w % nbn, bm = w / nbn;

  const int tid = threadIdx.x;
  const int wave = tid >> 6, lane = tid & 63;
  const int l15 = lane & 15, l4 = lane >> 4;
  const int wm = (BN == 256) ? (wave >> 2) : (wave >> 1);
  const int wn = (BN == 256) ? (wave & 3) : (wave & 1);
  const int nk = K >> 6;

  // staging source: row r within 16-row group = lane>>2; swizzled 16B chunk.
  // chunk XOR uses (row>>2)&3 so read-side bank_base = 16*(row&1)+4*chunk
  // gets exactly 2 lanes per bank (free); (row&3) would give 4-way.
  const int srow = lane >> 2;
  const int schunk = ((lane & 3) ^ ((srow >> 2) & 3)) << 4;
  const char* Ab = (const char*)A;
  const char* Bb = (const char*)Bt;
  const int arowA = wave * 32 + srow;
  const int arowB = (LB == 2) ? (wave * 32 + srow) : (wave * 16 + srow);

  auto stageA = [&](int buf, int kh, int kt) {
    const int ktA = (kdup && kt >= kdup) ? kt - kdup : kt;
    const char* s =
        Ab + (size_t)(bm * 256 + arowA) * (size_t)(lda * 2) + ktA * 128 +
        kh * 64 + schunk;
    char* d = lds + (((buf << 1) | kh) * ASZ) + wave * 2048;
    gload16(s, d);
    gload16(s + (size_t)16 * (size_t)(lda * 2), d + 1024);
  };
  auto stageB = [&](int buf, int kh, int kt) {
    const char* s = Bb + (size_t)(bn * BN + arowB) * (size_t)(K * 2) +
                    kt * 128 + kh * 64 + schunk;
    char* d = lds + ATOT + (((buf << 1) | kh) * BSZ) + wave * (LB * 1024);
    gload16(s, d);
    if (LB == 2) gload16(s + (size_t)16 * (size_t)(K * 2), d + 1024);
  };

  const f32x4 fz = {0.f, 0.f, 0.f, 0.f};
  f32x4 acc[MF][4];
#pragma unroll
  for (int i = 0; i < MF; ++i)
#pragma unroll
    for (int j = 0; j < 4; ++j) acc[i][j] = fz;

  // prologue: tile0 full + tile1 kh0, in steady-state issue order
  stageA(0, 0, 0);
  stageB(0, 0, 0);
  stageA(0, 1, 0);
  stageB(0, 1, 0);
  {
    const int k1 = (1 < nk) ? 1 : nk - 1;
    stageA(1, 0, k1);
    stageB(1, 0, k1);
  }
  asm volatile("s_waitcnt vmcnt(%0)" ::"i"(NWAIT) : "memory");
  __builtin_amdgcn_s_barrier();

  bf16x8 bq_[4];
  for (int u = 0; u < nk; ++u) {
    const int cur = u & 1;
    const int kp1 = (u + 1 < nk) ? u + 1 : nk - 1;
    const int kp2 = (u + 2 < nk) ? u + 2 : nk - 1;
#pragma unroll
    for (int p = 0; p < 4; ++p) {
      const int kh = p >> 1, mh = p & 1;
      bf16x8 af[MF / 2];
#pragma unroll
      for (int mi = 0; mi < MF / 2; ++mi) {
        const int m = wm * MPW + mh * (MPW / 2) + mi * 16 + l15;
        af[mi] = *(const bf16x8*)(lds + ((cur << 1) | kh) * ASZ + m * 64 +
                                  ((l4 ^ ((m >> 2) & 3)) << 4));
      }
      if (mh == 0) {
#pragma unroll
        for (int ni = 0; ni < 4; ++ni) {
          const int n = wn * 64 + ni * 16 + l15;
          bq_[ni] = *(const bf16x8*)(lds + ATOT + ((cur << 1) | kh) * BSZ +
                                     n * 64 + ((l4 ^ ((n >> 2) & 3)) << 4));
        }
      }
      if (p == 0)
        stageA(cur ^ 1, 1, kp1);
      else if (p == 1)
        stageB(cur ^ 1, 1, kp1);
      else if (p == 2)
        stageA(cur, 0, kp2);
      else
        stageB(cur, 0, kp2);
      __builtin_amdgcn_s_barrier();
      asm volatile("s_waitcnt lgkmcnt(0)" ::: "memory");
      __builtin_amdgcn_s_setprio(1);
#pragma unroll
      for (int mi = 0; mi < MF / 2; ++mi)
#pragma unroll
        for (int ni = 0; ni < 4; ++ni)
          acc[mh * (MF / 2) + mi][ni] =
              mfma16(af[mi], bq_[ni], acc[mh * (MF / 2) + mi][ni]);
      __builtin_amdgcn_s_setprio(0);
      if (p == 1 || p == 3)
        asm volatile("s_waitcnt vmcnt(%0)" ::"i"(NWAIT) : "memory");
      __builtin_amdgcn_s_barrier();
    }
  }
  asm volatile("s_waitcnt vmcnt(0)" ::: "memory");

  // ---- epilogue ----
#pragma unroll
  for (int mf = 0; mf < MF; ++mf) {
#pragma unroll
    for (int ni = 0; ni < 4; ++ni) {
      const int gn = bn * BN + wn * 64 + ni * 16 + l15;
      const float bia = bias[gn];
#pragma unroll
      for (int r = 0; r < 4; ++r) {
        const int gm = bm * 256 + wm * MPW + mf * 16 + l4 * 4 + r;
        float v = acc[mf][ni][r] + bia;
        if (EPI == EPI_BF16) {
          ((u16*)Cout)[(size_t)gm * ldc + gn] = f2b(v);
        } else if (EPI == EPI_RELU) {
          ((u16*)Cout)[(size_t)gm * ldc + gn] = f2b(v > 0.f ? v : 0.f);
        } else if (EPI == EPI_RES) {
          ((float*)Cout)[(size_t)gm * ldc + gn] =
              v + res[(size_t)gm * ldc + gn];
        } else if (EPI == EPI_SPLIT) {  // [hi | lo] planes within row
          u16 hi = f2b(v);
          ((u16*)Cout)[(size_t)gm * ldc + gn] = hi;
          ((u16*)Cout)[(size_t)gm * ldc + N + gn] = f2b(v - b2f(hi));
        } else if (EPI == EPI_QKFRAG) {
          // gm=(b,s); gn<1024: q -> Cout frags; gn>=1024: k -> Cout2.
          const int b = gm >> 9, s = gm & 511;
          const int gs = s >> 4, sr = s & 15;
          const int n = gn & 1023;
          const int h = n >> 6, e = n & 63;
          u16* base = (u16*)((gn >> 10) ? Cout2 : Cout);
          const size_t blk = ((size_t)(b * 16 + h) * 32 + gs) * 4;
          const int idx = ((e >> 3) & 3) * 128 + sr * 8 + (e & 7);
          const u16 hi = f2b(v);
          base[(blk + (e >> 5)) * 512 + idx] = hi;
          base[(blk + 2 + (e >> 5)) * 512 + idx] = f2b(v - b2f(hi));
        } else {  // EPI_VFRAG: B-operand frag for PV
          const int b = gm >> 9, s = gm & 511;
          const int h = gn >> 6, e = gn & 63;
          const size_t blk =
              ((size_t)(b * 16 + h) * 16 + (s >> 5)) * 4 + (e >> 4);
          ((u16*)Cout)[blk * 512 + ((s >> 3) & 3) * 128 + (e & 15) * 8 +
                       (s & 7)] = f2b(v);
        }
      }
    }
  }
}

// ---------------------------------------------------------------------------
// LayerNorm row kernel. SPLIT: out row = [hi(1024) | lo(1024)] (stride 2048).
// ---------------------------------------------------------------------------
template <bool SPLIT>
__global__ __launch_bounds__(256) void lnorm(const float* __restrict__ x,
                                             const float* __restrict__ g,
                                             const float* __restrict__ bt,
                                             u16* __restrict__ out) {
  const int row = blockIdx.x, tid = threadIdx.x;
  const int wave = tid >> 6, lane = tid & 63;
  const float4 v = *(const float4*)(x + (size_t)row * 1024 + tid * 4);
  float xv[4] = {v.x, v.y, v.z, v.w};
  float s = xv[0] + xv[1] + xv[2] + xv[3];
  float s2 = xv[0] * xv[0] + xv[1] * xv[1] + xv[2] * xv[2] + xv[3] * xv[3];
  for (int off = 32; off; off >>= 1) {
    s += __shfl_down(s, off);
    s2 += __shfl_down(s2, off);
  }
  __shared__ float red[8];
  if (lane == 0) {
    red[wave] = s;
    red[4 + wave] = s2;
  }
  __syncthreads();
  const float ts = red[0] + red[1] + red[2] + red[3];
  const float ts2 = red[4] + red[5] + red[6] + red[7];
  const float mean = ts * (1.f / 1024.f);
  const float var = ts2 * (1.f / 1024.f) - mean * mean;
  const float rstd = rsqrtf(var + 1e-5f);
#pragma unroll
  for (int j = 0; j < 4; ++j) {
    const int col = tid * 4 + j;
    const float y = (xv[j] - mean) * rstd * g[col] + bt[col];
    const u16 hi = f2b(y);
    if (SPLIT) {
      out[(size_t)row * 2048 + col] = hi;
      out[(size_t)row * 2048 + 1024 + col] = f2b(y - b2f(hi));
    } else {
      out[(size_t)row * 1024 + col] = hi;
    }
  }
}

// ---------------------------------------------------------------------------
// Weight transpose f32[K][cols] -> bf16 out[n][k] (row stride ors).
// SPLIT: out row = [hi | lo | hi] at offsets {0, Koff, 2*Koff}.
// grid: (cols/64, K/64, batch)
// ---------------------------------------------------------------------------
template <bool SPLIT>
__global__ __launch_bounds__(256) void wtrans(const float* __restrict__ in,
                                              int kstride, long ibs,
                                              u16* __restrict__ out, int ors,
                                              long obs, int Koff) {
  in += (size_t)blockIdx.z * ibs;
  out += (size_t)blockIdx.z * obs;
  const int n0 = blockIdx.x * 64, k0 = blockIdx.y * 64;
  const int tid = threadIdx.x;
  __shared__ float tt[64][65];
  const int r = tid >> 4, c4 = (tid & 15) * 4;
#pragma unroll
  for (int p = 0; p < 4; ++p) {
    const int rr = r + p * 16;
    const float4 vv =
        *(const float4*)(in + (size_t)(k0 + rr) * kstride + n0 + c4);
    tt[rr][c4] = vv.x;
    tt[rr][c4 + 1] = vv.y;
    tt[rr][c4 + 2] = vv.z;
    tt[rr][c4 + 3] = vv.w;
  }
  __syncthreads();
  const int nl = tid >> 2, kc = (tid & 3) * 16;
  u16 hi[16], lo[16];
#pragma unroll
  for (int j = 0; j < 16; ++j) {
    const float w = tt[kc + j][nl];
    hi[j] = f2b(w);
    if (SPLIT) lo[j] = f2b(w - b2f(hi[j]));
  }
  u16* orow = out + (size_t)(n0 + nl) * ors + k0 + kc;
  u16x8 a, b;
#pragma unroll
  for (int j = 0; j < 8; ++j) {
    a[j] = hi[j];
    b[j] = hi[8 + j];
  }
  *(u16x8*)(orow) = a;
  *(u16x8*)(orow + 8) = b;
  if (SPLIT) {
    *(u16x8*)(orow + 2 * Koff) = a;
    *(u16x8*)(orow + 2 * Koff + 8) = b;
    u16x8 c, d;
#pragma unroll
    for (int j = 0; j < 8; ++j) {
      c[j] = lo[j];
      d[j] = lo[8 + j];
    }
    *(u16x8*)(orow + Koff) = c;
    *(u16x8*)(orow + Koff + 8) = d;
  }
}

__global__ void biascat(const float* __restrict__ bq,
                        const float* __restrict__ bk, float* __restrict__ o) {
  const int i = blockIdx.x * 256 + threadIdx.x;  // 2048 total
  o[i] = (i < 1024) ? bq[i] : bk[i - 1024];
}

__global__ void fillconst(float* __restrict__ p, float v, int n) {
  const int i = blockIdx.x * 256 + threadIdx.x;
  if (i < n) p[i] = v;
}

// ---------------------------------------------------------------------------
// Flash attention (fragment layouts, 64-s iterations) — verified round 3.
// ---------------------------------------------------------------------------
__global__ __launch_bounds__(256) void attn_fwd(const u16* __restrict__ qf,
                                                const u16* __restrict__ kf,
                                                const u16* __restrict__ vf,
                                                u16* __restrict__ o) {
  const int bh = blockIdx.y;
  const int b = bh >> 4, h = bh & 15;
  const int xt = 7 - (int)blockIdx.x;  // heavy tiles dispatch first
  const int tid = threadIdx.x, wave = tid >> 6, lane = tid & 63;
  const int l15 = lane & 15, l4 = lane >> 4;
  const int gt = xt * 4 + wave;  // 16-row t-group, 0..31
  const int tw = gt * 16;
  __shared__ u16 Pl[4][1024];  // per-wave 16x64 bf16 P, 128B rows, swizzled

  const u16* kfb = kf + ((size_t)(bh * 32 + gt) * 4) * 512 + lane * 8;
  const bf16x8 kh0 = *(const bf16x8*)(kfb);
  const bf16x8 kh1 = *(const bf16x8*)(kfb + 512);
  const bf16x8 kl0 = *(const bf16x8*)(kfb + 1024);
  const bf16x8 kl1 = *(const bf16x8*)(kfb + 1536);

  const f32x4 fz = {0.f, 0.f, 0.f, 0.f};
  f32x4 oacc[4] = {fz, fz, fz, fz};
  float mrow[4] = {-1e30f, -1e30f, -1e30f, -1e30f};
  float lrow[4] = {0.f, 0.f, 0.f, 0.f};
  const u16* qfb = qf + (size_t)bh * 32 * 2048 + lane * 8;
  const u16* vfb = vf + (size_t)bh * 16 * 2048 + lane * 8;
  const int niter = (tw + 79) >> 6;

  for (int it = 0; it < niter; ++it) {
    const int s0 = it * 64;
    bf16x8 qh[4][2], ql[4][2];
#pragma unroll
    for (int scb = 0; scb < 4; ++scb) {
      const u16* qp = qfb + (size_t)((s0 >> 4) + scb) * 2048;
      qh[scb][0] = *(const bf16x8*)(qp);
      qh[scb][1] = *(const bf16x8*)(qp + 512);
      ql[scb][0] = *(const bf16x8*)(qp + 1024);
      ql[scb][1] = *(const bf16x8*)(qp + 1536);
    }
    bf16x8 vv[2][4];
#pragma unroll
    for (int h2 = 0; h2 < 2; ++h2) {
      const u16* vp = vfb + (size_t)((s0 >> 5) + h2) * 2048;
#pragma unroll
      for (int eF = 0; eF < 4; ++eF)
        vv[h2][eF] = *(const bf16x8*)(vp + eF * 512);
    }
    f32x4 sf[4];
#pragma unroll
    for (int scb = 0; scb < 4; ++scb) {
      f32x4 z = fz;
      z = mfma16(kh0, qh[scb][0], z);
      z = mfma16(kh1, qh[scb][1], z);
      z = mfma16(kh0, ql[scb][0], z);
      z = mfma16(kh1, ql[scb][1], z);
      z = mfma16(kl0, qh[scb][0], z);
      z = mfma16(kl1, qh[scb][1], z);
      sf[scb] = z;
    }
    if (s0 + 63 > tw) {
#pragma unroll
      for (int scb = 0; scb < 4; ++scb)
#pragma unroll
        for (int r = 0; r < 4; ++r) {
          const int s = s0 + scb * 16 + l15, t = tw + l4 * 4 + r;
          if (s > t) sf[scb][r] = -1e30f;
        }
    }
    float scl[4];
#pragma unroll
    for (int r = 0; r < 4; ++r) {
      float v = fmaxf(fmaxf(sf[0][r], sf[1][r]), fmaxf(sf[2][r], sf[3][r]));
      v = fmaxf(v, __shfl_xor(v, 1));
      v = fmaxf(v, __shfl_xor(v, 2));
      v = fmaxf(v, __shfl_xor(v, 4));
      v = fmaxf(v, __shfl_xor(v, 8));
      const float mn = fmaxf(mrow[r], v);
      scl[r] = __expf(mrow[r] - mn);
      mrow[r] = mn;
    }
    float ps[4] = {0.f, 0.f, 0.f, 0.f};
#pragma unroll
    for (int scb = 0; scb < 4; ++scb)
#pragma unroll
      for (int r = 0; r < 4; ++r) {
        const float p = __expf(sf[scb][r] - mrow[r]);
        sf[scb][r] = p;
        ps[r] += p;
      }
#pragma unroll
    for (int r = 0; r < 4; ++r) {
      float v = ps[r];
      v += __shfl_xor(v, 1);
      v += __shfl_xor(v, 2);
      v += __shfl_xor(v, 4);
      v += __shfl_xor(v, 8);
      lrow[r] = lrow[r] * scl[r] + v;
      oacc[0][r] *= scl[r];
      oacc[1][r] *= scl[r];
      oacc[2][r] *= scl[r];
      oacc[3][r] *= scl[r];
    }
#pragma unroll
    for (int scb = 0; scb < 4; ++scb)
#pragma unroll
      for (int r = 0; r < 4; ++r) {
        const int trow = l4 * 4 + r, scol = scb * 16 + l15;
        const int byte = trow * 128 + ((scol * 2) ^ ((trow & 7) << 4));
        *(u16*)((char*)&Pl[wave][0] + byte) = f2b(sf[scb][r]);
      }
#pragma unroll
    for (int h2 = 0; h2 < 2; ++h2) {
      const bf16x8 pf = *(const bf16x8*)((const char*)&Pl[wave][0] +
                                         l15 * 128 +
                                         (((h2 * 4 + l4) ^ (l15 & 7)) << 4));
#pragma unroll
      for (int eF = 0; eF < 4; ++eF)
        oacc[eF] = mfma16(pf, vv[h2][eF], oacc[eF]);
    }
  }
#pragma unroll
  for (int eF = 0; eF < 4; ++eF)
#pragma unroll
    for (int r = 0; r < 4; ++r) {
      const int t = tw + l4 * 4 + r;
      const float val = oacc[eF][r] / lrow[r];
      o[(size_t)(b * 512 + t) * 1024 + h * 64 + eF * 16 + l15] = f2b(val);
    }
}

// ---------------------------------------------------------------------------
extern "C" void kernel_launch(void* const* d_in, const int* in_sizes, int n_in,
                              void* d_out, int out_size, void* d_ws,
                              size_t ws_size, hipStream_t stream) {
  const float* x = (const float*)d_in[0];
  const float* ga = (const float*)d_in[1];
  const float* ba = (const float*)d_in[2];
  const float* Win = (const float*)d_in[3];
  const float* bin = (const float*)d_in[4];
  const float* Wk = (const float*)d_in[5];
  const float* bk = (const float*)d_in[6];
  const float* Wq = (const float*)d_in[7];
  const float* bq = (const float*)d_in[8];
  const float* Wv = (const float*)d_in[9];
  const float* bv = (const float*)d_in[10];
  const float* Wout = (const float*)d_in[11];
  const float* bout = (const float*)d_in[12];
  const float* gf = (const float*)d_in[13];
  const float* bf_ = (const float*)d_in[14];
  const float* W1 = (const float*)d_in[15];
  const float* b1 = (const float*)d_in[16];
  const float* W2 = (const float*)d_in[17];
  const float* b2 = (const float*)d_in[18];
  float* out = (float*)d_out;

  char* ws = (char*)d_ws;
  size_t off = 0;
  auto alloc = [&](size_t bytes) {
    char* p = ws + off;
    off += (bytes + 255) & ~(size_t)255;
    return p;
  };
  u16* WinT = (u16*)alloc((size_t)1024 * 3072 * 2);  // [n][hi|lo|hi]
  u16* WqkT = (u16*)alloc((size_t)2048 * 3072 * 2);  // rows 0..1023 q, rest k
  u16* WvT = (u16*)alloc((size_t)1024 * 1024 * 2);
  u16* WoutT = (u16*)alloc((size_t)1024 * 1024 * 2);
  u16* W1T = (u16*)alloc((size_t)4096 * 1024 * 2);
  u16* W2T = (u16*)alloc((size_t)1024 * 4096 * 2);
  float* bqk = (float*)alloc(2048 * 4);
  char* R1 = alloc((size_t)8192 * 2048 * 2);  // ln1 -> vf
  char* R2 = alloc((size_t)8192 * 2048 * 2);  // hb  -> ob, ln2
  char* QK = alloc((size_t)2 * 256 * 32 * 4 * 1024);  // qf+kf (64MB) -> ffn1
  const size_t need = off;                            // ~167 MiB

  if (need > ws_size) {  // diagnostic sentinel: ws too small -> absmax ~12345
    fillconst<<<(out_size + 255) / 256, 256, 0, stream>>>(out, 12345.0f,
                                                          out_size);
    return;
  }

  u16* ln1 = (u16*)R1;                              // 32 MiB
  u16* vfb = (u16*)R1;                              // 16 MiB, after ln1 dead
  u16* hb = (u16*)R2;                               // 32 MiB
  u16* ob = (u16*)R2;                               // after hb dead
  u16* ln2 = (u16*)(R2 + (size_t)8192 * 1024 * 2);  // second 16 MiB
  u16* qfb = (u16*)QK;                              // 32 MiB
  u16* kfb = (u16*)(QK + (size_t)256 * 32 * 4 * 1024);  // 32 MiB
  u16* ffn1 = (u16*)QK;                             // after attn, qf/kf dead
  float* x2 = out;                                  // d_out doubles as x2

  // ---- weight prep (bf16 [+split] transposes) ----
  wtrans<true><<<dim3(16, 16, 1), 256, 0, stream>>>(Win, 1024, 0, WinT, 3072,
                                                    0, 1024);
  wtrans<true><<<dim3(1, 16, 16), 256, 0, stream>>>(Wq, 64, 65536, WqkT, 3072,
                                                    (long)64 * 3072, 1024);
  wtrans<true><<<dim3(1, 16, 16), 256, 0, stream>>>(
      Wk, 64, 65536, WqkT + (size_t)1024 * 3072, 3072, (long)64 * 3072, 1024);
  wtrans<false><<<dim3(1, 16, 16), 256, 0, stream>>>(Wv, 64, 65536, WvT, 1024,
                                                     (long)64 * 1024, 0);
  wtrans<false><<<dim3(16, 16, 1), 256, 0, stream>>>(Wout, 1024, 0, WoutT,
                                                     1024, 0, 0);
  wtrans<false><<<dim3(64, 16, 1), 256, 0, stream>>>(W1, 4096, 0, W1T, 1024, 0,
                                                     0);
  wtrans<false><<<dim3(16, 64, 1), 256, 0, stream>>>(W2, 1024, 0, W2T, 4096, 0,
                                                     0);
  biascat<<<8, 256, 0, stream>>>(bq, bk, bqk);

  // ---- pipeline ----
  lnorm<true><<<8192, 256, 0, stream>>>(x, ga, ba, ln1);
  // h = ln1 @ Win + bin  (split-K 3072, split output)
  gemm256<128, EPI_SPLIT><<<256, 512, 0, stream>>>(
      ln1, 2048, 16, WinT, bin, nullptr, hb, nullptr, 2048, 1024, 3072);
  // [q|k] = h @ [Wq|Wk]  (split-K, fragment-layout split output)
  gemm256<256, EPI_QKFRAG><<<256, 512, 0, stream>>>(
      hb, 2048, 16, WqkT, bqk, nullptr, qfb, kfb, 0, 2048, 3072);
  // v = h_hi @ Wv + bv  (fragment layout, overwrites ln1 region: dead)
  gemm256<128, EPI_VFRAG><<<256, 512, 0, stream>>>(
      hb, 2048, 0, WvT, bv, nullptr, vfb, nullptr, 0, 1024, 1024);
  attn_fwd<<<dim3(8, 256), 256, 0, stream>>>(qfb, kfb, vfb, ob);
  // x2 = o @ Wout + bout + x   (x2 == d_out)
  gemm256<128, EPI_RES><<<256, 512, 0, stream>>>(
      ob, 1024, 0, WoutT, bout, x, x2, nullptr, 1024, 1024, 1024);
  lnorm<false><<<8192, 256, 0, stream>>>(x2, gf, bf_, ln2);
  // ffn1 = relu(ln2 @ W1 + b1)   (overwrites qf/kf region: dead)
  gemm256<256, EPI_RELU><<<512, 512, 0, stream>>>(
      ln2, 1024, 0, W1T, b1, nullptr, ffn1, nullptr, 4096, 4096, 1024);
  // out = ffn1 @ W2 + b2 + x2   (res == Cout == d_out, element-wise safe)
  gemm256<128, EPI_RES><<<256, 512, 0, stream>>>(
      ffn1, 4096, 0, W2T, b2, x2, out, nullptr, 1024, 1024, 4096);
}

// Round 6
// 493.249 us; speedup vs baseline: 1.0355x; 1.0355x over previous
//
#include <hip/hip_runtime.h>

// ---------------------------------------------------------------------------
// Transformer block (pre-LN attn + FFN), B=16 T=512 D=1024 H=16 HD=64, f32 io.
// bf16 MFMA GEMMs; q/k path uses bf16 hi/lo split (K'=3K GEMM) so the
// UNSCALED K.Q^T scores stay ~f32-accurate.
// GEMM v2.2: 256xBN tile, BK=64, 8 waves, 4-phase/K-tile schedule, counted
// vmcnt (never 0 in loop), raw s_barrier, setprio around MFMA clusters,
// 2-K-tile prefetch, XCD swizzle.
// Swizzle derivation (v2/v2.1 had 2-lanes-per-bank-group, 9.4M conflicts):
//   64B rows -> bank_base = 16*(row&1) + 4*chunk. Read group = 16 lanes,
//   rows 16k+l15, chunk l4^f(row). Need (row&1, chunk) bijective over any
//   8 consecutive rows -> f(row) = (row>>1)&3. (row&3 and (row>>2)&3 both
//   alias rows m, m+4 -> same bank group.)
// Attention: fragment-layout flash, 64-s iterations (verified round 3).
// Workspace (~167 MiB, liveness-aliased), x2 lives in d_out.
// ---------------------------------------------------------------------------

#define DEV __device__ __forceinline__

typedef unsigned short u16;
typedef __attribute__((ext_vector_type(8))) __bf16 bf16x8;
typedef __attribute__((ext_vector_type(4))) float f32x4;
typedef __attribute__((ext_vector_type(8))) unsigned short u16x8;

typedef __attribute__((address_space(1))) void as1_void;
typedef __attribute__((address_space(3))) void as3_void;

DEV u16 f2b(float f) {                       // f32 -> bf16 RNE (finite inputs)
  unsigned u = __float_as_uint(f);
  u = (u + 0x7fffu + ((u >> 16) & 1u)) >> 16;
  return (u16)u;
}
DEV float b2f(u16 h) { return __uint_as_float(((unsigned)h) << 16); }

DEV f32x4 mfma16(bf16x8 a, bf16x8 b, f32x4 c) {
  return __builtin_amdgcn_mfma_f32_16x16x32_bf16(a, b, c, 0, 0, 0);
}

// async global->LDS, 16B per lane, dest = uniform base + lane*16
DEV void gload16(const void* g, void* l) {
  __builtin_amdgcn_global_load_lds((as1_void*)(unsigned long long)g,
                                   (as3_void*)(unsigned long long)l,
                                   16u, 0, 0u);
}

#define EPI_BF16 0
#define EPI_RELU 1
#define EPI_RES 2
#define EPI_SPLIT 3
#define EPI_QKFRAG 4
#define EPI_VFRAG 5

// ---------------------------------------------------------------------------
// GEMM v2.2: C[M,N] = A[M,K]*Bt[N,K]^T + bias. BM=256, BK=64, 8 waves.
// Schedule per iteration u (buf cur=u&1), phases p=(kh,mh):
//   p0: read A(kh0,mh0)+B(kh0); stage (u+1).Akh1 -> buf cur^1
//   p1: read A(kh0,mh1);        stage (u+1).Bkh1; vmcnt(NW)
//   p2: read A(kh1,mh0)+B(kh1); stage (u+2).Akh0 -> buf cur
//   p3: read A(kh1,mh1);        stage (u+2).Bkh0; vmcnt(NW)
// NW = 2*(LA+LB); FIFO accounting verified. Tail staging clamps kt (dummy
// reloads keep vmcnt counts uniform; targets are dead regions).
// ---------------------------------------------------------------------------
template <int BN, int EPI>
__global__ __launch_bounds__(512, 2) void gemm256(
    const u16* __restrict__ A, int lda, int kdup, const u16* __restrict__ Bt,
    const float* __restrict__ bias, const float* __restrict__ res,
    void* __restrict__ Cout, void* __restrict__ Cout2, int ldc, int N, int K) {
  constexpr int MPW = (BN == 256) ? 128 : 64;  // per-wave m rows
  constexpr int MF = MPW / 16;                 // m-frags per wave (8 or 4)
  constexpr int LA = 2;                        // A gloads/thread/stage-phase
  constexpr int LB = BN / 128;                 // B gloads/thread/stage-phase
  constexpr int NWAIT = 2 * (LA + LB);         // counted vmcnt
  constexpr int ASZ = 256 * 64;                // bytes per (buf,kh) A region
  constexpr int BSZ = BN * 64;
  constexpr int ATOT = 4 * ASZ;
  __shared__ __align__(1024) char lds[4 * ASZ + 4 * BSZ];

  // XCD-contiguous block swizzle (gridDim.x % 8 == 0 by construction)
  const int nwg = (int)gridDim.x;
  const int cpx = nwg >> 3;
  int w = (int)blockIdx.x;
  w = (w & 7) * cpx + (w >> 3);
  const int nbn = N / BN;
  const int bn = w % nbn, bm = w / nbn;

  const int tid = threadIdx.x;
  const int wave = tid >> 6, lane = tid & 63;
  const int l15 = lane & 15, l4 = lane >> 4;
  const int wm = (BN == 256) ? (wave >> 2) : (wave >> 1);
  const int wn = (BN == 256) ? (wave & 3) : (wave & 1);
  const int nk = K >> 6;

  // staging source: dest row-in-16-group = lane>>2, dest chunk = lane&3;
  // source holds chunk (lane&3) ^ ((row>>1)&3)  [same involution as reads]
  const int srow = lane >> 2;
  const int schunk = ((lane & 3) ^ ((srow >> 1) & 3)) << 4;
  const char* Ab = (const char*)A;
  const char* Bb = (const char*)Bt;
  const int arowA = wave * 32 + srow;
  const int arowB = (LB == 2) ? (wave * 32 + srow) : (wave * 16 + srow);

  auto stageA = [&](int buf, int kh, int kt) {
    const int ktA = (kdup && kt >= kdup) ? kt - kdup : kt;
    const char* s =
        Ab + (size_t)(bm * 256 + arowA) * (size_t)(lda * 2) + ktA * 128 +
        kh * 64 + schunk;
    char* d = lds + (((buf << 1) | kh) * ASZ) + wave * 2048;
    gload16(s, d);
    gload16(s + (size_t)16 * (size_t)(lda * 2), d + 1024);
  };
  auto stageB = [&](int buf, int kh, int kt) {
    const char* s = Bb + (size_t)(bn * BN + arowB) * (size_t)(K * 2) +
                    kt * 128 + kh * 64 + schunk;
    char* d = lds + ATOT + (((buf << 1) | kh) * BSZ) + wave * (LB * 1024);
    gload16(s, d);
    if (LB == 2) gload16(s + (size_t)16 * (size_t)(K * 2), d + 1024);
  };

  const f32x4 fz = {0.f, 0.f, 0.f, 0.f};
  f32x4 acc[MF][4];
#pragma unroll
  for (int i = 0; i < MF; ++i)
#pragma unroll
    for (int j = 0; j < 4; ++j) acc[i][j] = fz;

  // prologue: tile0 full + tile1 kh0, in steady-state issue order
  stageA(0, 0, 0);
  stageB(0, 0, 0);
  stageA(0, 1, 0);
  stageB(0, 1, 0);
  {
    const int k1 = (1 < nk) ? 1 : nk - 1;
    stageA(1, 0, k1);
    stageB(1, 0, k1);
  }
  asm volatile("s_waitcnt vmcnt(%0)" ::"i"(NWAIT) : "memory");
  __builtin_amdgcn_s_barrier();

  bf16x8 bq_[4];
  for (int u = 0; u < nk; ++u) {
    const int cur = u & 1;
    const int kp1 = (u + 1 < nk) ? u + 1 : nk - 1;
    const int kp2 = (u + 2 < nk) ? u + 2 : nk - 1;
#pragma unroll
    for (int p = 0; p < 4; ++p) {
      const int kh = p >> 1, mh = p & 1;
      bf16x8 af[MF / 2];
#pragma unroll
      for (int mi = 0; mi < MF / 2; ++mi) {
        const int m = wm * MPW + mh * (MPW / 2) + mi * 16 + l15;
        af[mi] = *(const bf16x8*)(lds + ((cur << 1) | kh) * ASZ + m * 64 +
                                  ((l4 ^ ((m >> 1) & 3)) << 4));
      }
      if (mh == 0) {
#pragma unroll
        for (int ni = 0; ni < 4; ++ni) {
          const int n = wn * 64 + ni * 16 + l15;
          bq_[ni] = *(const bf16x8*)(lds + ATOT + ((cur << 1) | kh) * BSZ +
                                     n * 64 + ((l4 ^ ((n >> 1) & 3)) << 4));
        }
      }
      if (p == 0)
        stageA(cur ^ 1, 1, kp1);
      else if (p == 1)
        stageB(cur ^ 1, 1, kp1);
      else if (p == 2)
        stageA(cur, 0, kp2);
      else
        stageB(cur, 0, kp2);
      __builtin_amdgcn_s_barrier();
      asm volatile("s_waitcnt lgkmcnt(0)" ::: "memory");
      __builtin_amdgcn_s_setprio(1);
#pragma unroll
      for (int mi = 0; mi < MF / 2; ++mi)
#pragma unroll
        for (int ni = 0; ni < 4; ++ni)
          acc[mh * (MF / 2) + mi][ni] =
              mfma16(af[mi], bq_[ni], acc[mh * (MF / 2) + mi][ni]);
      __builtin_amdgcn_s_setprio(0);
      if (p == 1 || p == 3)
        asm volatile("s_waitcnt vmcnt(%0)" ::"i"(NWAIT) : "memory");
      __builtin_amdgcn_s_barrier();
    }
  }
  asm volatile("s_waitcnt vmcnt(0)" ::: "memory");

  // ---- epilogue ----
#pragma unroll
  for (int mf = 0; mf < MF; ++mf) {
#pragma unroll
    for (int ni = 0; ni < 4; ++ni) {
      const int gn = bn * BN + wn * 64 + ni * 16 + l15;
      const float bia = bias[gn];
#pragma unroll
      for (int r = 0; r < 4; ++r) {
        const int gm = bm * 256 + wm * MPW + mf * 16 + l4 * 4 + r;
        float v = acc[mf][ni][r] + bia;
        if (EPI == EPI_BF16) {
          ((u16*)Cout)[(size_t)gm * ldc + gn] = f2b(v);
        } else if (EPI == EPI_RELU) {
          ((u16*)Cout)[(size_t)gm * ldc + gn] = f2b(v > 0.f ? v : 0.f);
        } else if (EPI == EPI_RES) {
          ((float*)Cout)[(size_t)gm * ldc + gn] =
              v + res[(size_t)gm * ldc + gn];
        } else if (EPI == EPI_SPLIT) {  // [hi | lo] planes within row
          u16 hi = f2b(v);
          ((u16*)Cout)[(size_t)gm * ldc + gn] = hi;
          ((u16*)Cout)[(size_t)gm * ldc + N + gn] = f2b(v - b2f(hi));
        } else if (EPI == EPI_QKFRAG) {
          // gm=(b,s); gn<1024: q -> Cout frags; gn>=1024: k -> Cout2.
          const int b = gm >> 9, s = gm & 511;
          const int gs = s >> 4, sr = s & 15;
          const int n = gn & 1023;
          const int h = n >> 6, e = n & 63;
          u16* base = (u16*)((gn >> 10) ? Cout2 : Cout);
          const size_t blk = ((size_t)(b * 16 + h) * 32 + gs) * 4;
          const int idx = ((e >> 3) & 3) * 128 + sr * 8 + (e & 7);
          const u16 hi = f2b(v);
          base[(blk + (e >> 5)) * 512 + idx] = hi;
          base[(blk + 2 + (e >> 5)) * 512 + idx] = f2b(v - b2f(hi));
        } else {  // EPI_VFRAG: B-operand frag for PV
          const int b = gm >> 9, s = gm & 511;
          const int h = gn >> 6, e = gn & 63;
          const size_t blk =
              ((size_t)(b * 16 + h) * 16 + (s >> 5)) * 4 + (e >> 4);
          ((u16*)Cout)[blk * 512 + ((s >> 3) & 3) * 128 + (e & 15) * 8 +
                       (s & 7)] = f2b(v);
        }
      }
    }
  }
}

// ---------------------------------------------------------------------------
// LayerNorm row kernel. SPLIT: out row = [hi(1024) | lo(1024)] (stride 2048).
// ---------------------------------------------------------------------------
template <bool SPLIT>
__global__ __launch_bounds__(256) void lnorm(const float* __restrict__ x,
                                             const float* __restrict__ g,
                                             const float* __restrict__ bt,
                                             u16* __restrict__ out) {
  const int row = blockIdx.x, tid = threadIdx.x;
  const int wave = tid >> 6, lane = tid & 63;
  const float4 v = *(const float4*)(x + (size_t)row * 1024 + tid * 4);
  float xv[4] = {v.x, v.y, v.z, v.w};
  float s = xv[0] + xv[1] + xv[2] + xv[3];
  float s2 = xv[0] * xv[0] + xv[1] * xv[1] + xv[2] * xv[2] + xv[3] * xv[3];
  for (int off = 32; off; off >>= 1) {
    s += __shfl_down(s, off);
    s2 += __shfl_down(s2, off);
  }
  __shared__ float red[8];
  if (lane == 0) {
    red[wave] = s;
    red[4 + wave] = s2;
  }
  __syncthreads();
  const float ts = red[0] + red[1] + red[2] + red[3];
  const float ts2 = red[4] + red[5] + red[6] + red[7];
  const float mean = ts * (1.f / 1024.f);
  const float var = ts2 * (1.f / 1024.f) - mean * mean;
  const float rstd = rsqrtf(var + 1e-5f);
#pragma unroll
  for (int j = 0; j < 4; ++j) {
    const int col = tid * 4 + j;
    const float y = (xv[j] - mean) * rstd * g[col] + bt[col];
    const u16 hi = f2b(y);
    if (SPLIT) {
      out[(size_t)row * 2048 + col] = hi;
      out[(size_t)row * 2048 + 1024 + col] = f2b(y - b2f(hi));
    } else {
      out[(size_t)row * 1024 + col] = hi;
    }
  }
}

// ---------------------------------------------------------------------------
// Weight transpose f32[K][cols] -> bf16 out[n][k] (row stride ors).
// SPLIT: out row = [hi | lo | hi] at offsets {0, Koff, 2*Koff}.
// grid: (cols/64, K/64, batch)
// ---------------------------------------------------------------------------
template <bool SPLIT>
__global__ __launch_bounds__(256) void wtrans(const float* __restrict__ in,
                                              int kstride, long ibs,
                                              u16* __restrict__ out, int ors,
                                              long obs, int Koff) {
  in += (size_t)blockIdx.z * ibs;
  out += (size_t)blockIdx.z * obs;
  const int n0 = blockIdx.x * 64, k0 = blockIdx.y * 64;
  const int tid = threadIdx.x;
  __shared__ float tt[64][65];
  const int r = tid >> 4, c4 = (tid & 15) * 4;
#pragma unroll
  for (int p = 0; p < 4; ++p) {
    const int rr = r + p * 16;
    const float4 vv =
        *(const float4*)(in + (size_t)(k0 + rr) * kstride + n0 + c4);
    tt[rr][c4] = vv.x;
    tt[rr][c4 + 1] = vv.y;
    tt[rr][c4 + 2] = vv.z;
    tt[rr][c4 + 3] = vv.w;
  }
  __syncthreads();
  const int nl = tid >> 2, kc = (tid & 3) * 16;
  u16 hi[16], lo[16];
#pragma unroll
  for (int j = 0; j < 16; ++j) {
    const float w = tt[kc + j][nl];
    hi[j] = f2b(w);
    if (SPLIT) lo[j] = f2b(w - b2f(hi[j]));
  }
  u16* orow = out + (size_t)(n0 + nl) * ors + k0 + kc;
  u16x8 a, b;
#pragma unroll
  for (int j = 0; j < 8; ++j) {
    a[j] = hi[j];
    b[j] = hi[8 + j];
  }
  *(u16x8*)(orow) = a;
  *(u16x8*)(orow + 8) = b;
  if (SPLIT) {
    *(u16x8*)(orow + 2 * Koff) = a;
    *(u16x8*)(orow + 2 * Koff + 8) = b;
    u16x8 c, d;
#pragma unroll
    for (int j = 0; j < 8; ++j) {
      c[j] = lo[j];
      d[j] = lo[8 + j];
    }
    *(u16x8*)(orow + Koff) = c;
    *(u16x8*)(orow + Koff + 8) = d;
  }
}

__global__ void biascat(const float* __restrict__ bq,
                        const float* __restrict__ bk, float* __restrict__ o) {
  const int i = blockIdx.x * 256 + threadIdx.x;  // 2048 total
  o[i] = (i < 1024) ? bq[i] : bk[i - 1024];
}

__global__ void fillconst(float* __restrict__ p, float v, int n) {
  const int i = blockIdx.x * 256 + threadIdx.x;
  if (i < n) p[i] = v;
}

// ---------------------------------------------------------------------------
// Flash attention (fragment layouts, 64-s iterations) — verified round 3.
// ---------------------------------------------------------------------------
__global__ __launch_bounds__(256) void attn_fwd(const u16* __restrict__ qf,
                                                const u16* __restrict__ kf,
                                                const u16* __restrict__ vf,
                                                u16* __restrict__ o) {
  const int bh = blockIdx.y;
  const int b = bh >> 4, h = bh & 15;
  const int xt = 7 - (int)blockIdx.x;  // heavy tiles dispatch first
  const int tid = threadIdx.x, wave = tid >> 6, lane = tid & 63;
  const int l15 = lane & 15, l4 = lane >> 4;
  const int gt = xt * 4 + wave;  // 16-row t-group, 0..31
  const int tw = gt * 16;
  __shared__ u16 Pl[4][1024];  // per-wave 16x64 bf16 P, 128B rows, swizzled

  const u16* kfb = kf + ((size_t)(bh * 32 + gt) * 4) * 512 + lane * 8;
  const bf16x8 kh0 = *(const bf16x8*)(kfb);
  const bf16x8 kh1 = *(const bf16x8*)(kfb + 512);
  const bf16x8 kl0 = *(const bf16x8*)(kfb + 1024);
  const bf16x8 kl1 = *(const bf16x8*)(kfb + 1536);

  const f32x4 fz = {0.f, 0.f, 0.f, 0.f};
  f32x4 oacc[4] = {fz, fz, fz, fz};
  float mrow[4] = {-1e30f, -1e30f, -1e30f, -1e30f};
  float lrow[4] = {0.f, 0.f, 0.f, 0.f};
  const u16* qfb = qf + (size_t)bh * 32 * 2048 + lane * 8;
  const u16* vfb = vf + (size_t)bh * 16 * 2048 + lane * 8;
  const int niter = (tw + 79) >> 6;

  for (int it = 0; it < niter; ++it) {
    const int s0 = it * 64;
    bf16x8 qh[4][2], ql[4][2];
#pragma unroll
    for (int scb = 0; scb < 4; ++scb) {
      const u16* qp = qfb + (size_t)((s0 >> 4) + scb) * 2048;
      qh[scb][0] = *(const bf16x8*)(qp);
      qh[scb][1] = *(const bf16x8*)(qp + 512);
      ql[scb][0] = *(const bf16x8*)(qp + 1024);
      ql[scb][1] = *(const bf16x8*)(qp + 1536);
    }
    bf16x8 vv[2][4];
#pragma unroll
    for (int h2 = 0; h2 < 2; ++h2) {
      const u16* vp = vfb + (size_t)((s0 >> 5) + h2) * 2048;
#pragma unroll
      for (int eF = 0; eF < 4; ++eF)
        vv[h2][eF] = *(const bf16x8*)(vp + eF * 512);
    }
    f32x4 sf[4];
#pragma unroll
    for (int scb = 0; scb < 4; ++scb) {
      f32x4 z = fz;
      z = mfma16(kh0, qh[scb][0], z);
      z = mfma16(kh1, qh[scb][1], z);
      z = mfma16(kh0, ql[scb][0], z);
      z = mfma16(kh1, ql[scb][1], z);
      z = mfma16(kl0, qh[scb][0], z);
      z = mfma16(kl1, qh[scb][1], z);
      sf[scb] = z;
    }
    if (s0 + 63 > tw) {
#pragma unroll
      for (int scb = 0; scb < 4; ++scb)
#pragma unroll
        for (int r = 0; r < 4; ++r) {
          const int s = s0 + scb * 16 + l15, t = tw + l4 * 4 + r;
          if (s > t) sf[scb][r] = -1e30f;
        }
    }
    float scl[4];
#pragma unroll
    for (int r = 0; r < 4; ++r) {
      float v = fmaxf(fmaxf(sf[0][r], sf[1][r]), fmaxf(sf[2][r], sf[3][r]));
      v = fmaxf(v, __shfl_xor(v, 1));
      v = fmaxf(v, __shfl_xor(v, 2));
      v = fmaxf(v, __shfl_xor(v, 4));
      v = fmaxf(v, __shfl_xor(v, 8));
      const float mn = fmaxf(mrow[r], v);
      scl[r] = __expf(mrow[r] - mn);
      mrow[r] = mn;
    }
    float ps[4] = {0.f, 0.f, 0.f, 0.f};
#pragma unroll
    for (int scb = 0; scb < 4; ++scb)
#pragma unroll
      for (int r = 0; r < 4; ++r) {
        const float p = __expf(sf[scb][r] - mrow[r]);
        sf[scb][r] = p;
        ps[r] += p;
      }
#pragma unroll
    for (int r = 0; r < 4; ++r) {
      float v = ps[r];
      v += __shfl_xor(v, 1);
      v += __shfl_xor(v, 2);
      v += __shfl_xor(v, 4);
      v += __shfl_xor(v, 8);
      lrow[r] = lrow[r] * scl[r] + v;
      oacc[0][r] *= scl[r];
      oacc[1][r] *= scl[r];
      oacc[2][r] *= scl[r];
      oacc[3][r] *= scl[r];
    }
#pragma unroll
    for (int scb = 0; scb < 4; ++scb)
#pragma unroll
      for (int r = 0; r < 4; ++r) {
        const int trow = l4 * 4 + r, scol = scb * 16 + l15;
        const int byte = trow * 128 + ((scol * 2) ^ ((trow & 7) << 4));
        *(u16*)((char*)&Pl[wave][0] + byte) = f2b(sf[scb][r]);
      }
#pragma unroll
    for (int h2 = 0; h2 < 2; ++h2) {
      const bf16x8 pf = *(const bf16x8*)((const char*)&Pl[wave][0] +
                                         l15 * 128 +
                                         (((h2 * 4 + l4) ^ (l15 & 7)) << 4));
#pragma unroll
      for (int eF = 0; eF < 4; ++eF)
        oacc[eF] = mfma16(pf, vv[h2][eF], oacc[eF]);
    }
  }
#pragma unroll
  for (int eF = 0; eF < 4; ++eF)
#pragma unroll
    for (int r = 0; r < 4; ++r) {
      const int t = tw + l4 * 4 + r;
      const float val = oacc[eF][r] / lrow[r];
      o[(size_t)(b * 512 + t) * 1024 + h * 64 + eF * 16 + l15] = f2b(val);
    }
}

// ---------------------------------------------------------------------------
extern "C" void kernel_launch(void* const* d_in, const int* in_sizes, int n_in,
                              void* d_out, int out_size, void* d_ws,
                              size_t ws_size, hipStream_t stream) {
  const float* x = (const float*)d_in[0];
  const float* ga = (const float*)d_in[1];
  const float* ba = (const float*)d_in[2];
  const float* Win = (const float*)d_in[3];
  const float* bin = (const float*)d_in[4];
  const float* Wk = (const float*)d_in[5];
  const float* bk = (const float*)d_in[6];
  const float* Wq = (const float*)d_in[7];
  const float* bq = (const float*)d_in[8];
  const float* Wv = (const float*)d_in[9];
  const float* bv = (const float*)d_in[10];
  const float* Wout = (const float*)d_in[11];
  const float* bout = (const float*)d_in[12];
  const float* gf = (const float*)d_in[13];
  const float* bf_ = (const float*)d_in[14];
  const float* W1 = (const float*)d_in[15];
  const float* b1 = (const float*)d_in[16];
  const float* W2 = (const float*)d_in[17];
  const float* b2 = (const float*)d_in[18];
  float* out = (float*)d_out;

  char* ws = (char*)d_ws;
  size_t off = 0;
  auto alloc = [&](size_t bytes) {
    char* p = ws + off;
    off += (bytes + 255) & ~(size_t)255;
    return p;
  };
  u16* WinT = (u16*)alloc((size_t)1024 * 3072 * 2);  // [n][hi|lo|hi]
  u16* WqkT = (u16*)alloc((size_t)2048 * 3072 * 2);  // rows 0..1023 q, rest k
  u16* WvT = (u16*)alloc((size_t)1024 * 1024 * 2);
  u16* WoutT = (u16*)alloc((size_t)1024 * 1024 * 2);
  u16* W1T = (u16*)alloc((size_t)4096 * 1024 * 2);
  u16* W2T = (u16*)alloc((size_t)1024 * 4096 * 2);
  float* bqk = (float*)alloc(2048 * 4);
  char* R1 = alloc((size_t)8192 * 2048 * 2);  // ln1 -> vf
  char* R2 = alloc((size_t)8192 * 2048 * 2);  // hb  -> ob, ln2
  char* QK = alloc((size_t)2 * 256 * 32 * 4 * 1024);  // qf+kf (64MB) -> ffn1
  const size_t need = off;                            // ~167 MiB

  if (need > ws_size) {  // diagnostic sentinel: ws too small -> absmax ~12345
    fillconst<<<(out_size + 255) / 256, 256, 0, stream>>>(out, 12345.0f,
                                                          out_size);
    return;
  }

  u16* ln1 = (u16*)R1;                              // 32 MiB
  u16* vfb = (u16*)R1;                              // 16 MiB, after ln1 dead
  u16* hb = (u16*)R2;                               // 32 MiB
  u16* ob = (u16*)R2;                               // after hb dead
  u16* ln2 = (u16*)(R2 + (size_t)8192 * 1024 * 2);  // second 16 MiB
  u16* qfb = (u16*)QK;                              // 32 MiB
  u16* kfb = (u16*)(QK + (size_t)256 * 32 * 4 * 1024);  // 32 MiB
  u16* ffn1 = (u16*)QK;                             // after attn, qf/kf dead
  float* x2 = out;                                  // d_out doubles as x2

  // ---- weight prep (bf16 [+split] transposes) ----
  wtrans<true><<<dim3(16, 16, 1), 256, 0, stream>>>(Win, 1024, 0, WinT, 3072,
                                                    0, 1024);
  wtrans<true><<<dim3(1, 16, 16), 256, 0, stream>>>(Wq, 64, 65536, WqkT, 3072,
                                                    (long)64 * 3072, 1024);
  wtrans<true><<<dim3(1, 16, 16), 256, 0, stream>>>(
      Wk, 64, 65536, WqkT + (size_t)1024 * 3072, 3072, (long)64 * 3072, 1024);
  wtrans<false><<<dim3(1, 16, 16), 256, 0, stream>>>(Wv, 64, 65536, WvT, 1024,
                                                     (long)64 * 1024, 0);
  wtrans<false><<<dim3(16, 16, 1), 256, 0, stream>>>(Wout, 1024, 0, WoutT,
                                                     1024, 0, 0);
  wtrans<false><<<dim3(64, 16, 1), 256, 0, stream>>>(W1, 4096, 0, W1T, 1024, 0,
                                                     0);
  wtrans<false><<<dim3(16, 64, 1), 256, 0, stream>>>(W2, 1024, 0, W2T, 4096, 0,
                                                     0);
  biascat<<<8, 256, 0, stream>>>(bq, bk, bqk);

  // ---- pipeline ----
  lnorm<true><<<8192, 256, 0, stream>>>(x, ga, ba, ln1);
  // h = ln1 @ Win + bin  (split-K 3072, split output)
  gemm256<128, EPI_SPLIT><<<256, 512, 0, stream>>>(
      ln1, 2048, 16, WinT, bin, nullptr, hb, nullptr, 2048, 1024, 3072);
  // [q|k] = h @ [Wq|Wk]  (split-K, fragment-layout split output)
  gemm256<256, EPI_QKFRAG><<<256, 512, 0, stream>>>(
      hb, 2048, 16, WqkT, bqk, nullptr, qfb, kfb, 0, 2048, 3072);
  // v = h_hi @ Wv + bv  (fragment layout, overwrites ln1 region: dead)
  gemm256<128, EPI_VFRAG><<<256, 512, 0, stream>>>(
      hb, 2048, 0, WvT, bv, nullptr, vfb, nullptr, 0, 1024, 1024);
  attn_fwd<<<dim3(8, 256), 256, 0, stream>>>(qfb, kfb, vfb, ob);
  // x2 = o @ Wout + bout + x   (x2 == d_out)
  gemm256<128, EPI_RES><<<256, 512, 0, stream>>>(
      ob, 1024, 0, WoutT, bout, x, x2, nullptr, 1024, 1024, 1024);
  lnorm<false><<<8192, 256, 0, stream>>>(x2, gf, bf_, ln2);
  // ffn1 = relu(ln2 @ W1 + b1)   (overwrites qf/kf region: dead)
  gemm256<256, EPI_RELU><<<512, 512, 0, stream>>>(
      ln2, 1024, 0, W1T, b1, nullptr, ffn1, nullptr, 4096, 4096, 1024);
  // out = ffn1 @ W2 + b2 + x2   (res == Cout == d_out, element-wise safe)
  gemm256<128, EPI_RES><<<256, 512, 0, stream>>>(
      ffn1, 4096, 0, W2T, b2, x2, out, nullptr, 1024, 1024, 4096);
}

// Round 7
// 486.800 us; speedup vs baseline: 1.0492x; 1.0132x over previous
//
#include <hip/hip_runtime.h>

// ---------------------------------------------------------------------------
// Transformer block (pre-LN attn + FFN), B=16 T=512 D=1024 H=16 HD=64, f32 io.
// bf16 MFMA GEMMs; q/k path uses bf16 hi/lo split (K'=3K GEMM) so the
// UNSCALED K.Q^T scores stay ~f32-accurate.
// GEMM v3: 256xBN tile, BK=64, 8 waves, 2 kh-superphases per K-tile with
// only 2 barriers/K-tile. No forced lgkmcnt before MFMA (compiler emits
// fine-grained waits -> ds_read latency hides under MFMA). Counted vmcnt
// (never 0 in loop), conflict-free XOR swizzle (verified 0 conflicts r6),
// 2-K-tile prefetch, XCD swizzle, setprio around MFMA cluster.
// Superphase: reads(12) -> stage issue -> MFMA(32) -> lgkm0 (WAR: region
// re-staged next superphase) -> vmcnt(NW) (visibility) -> s_barrier.
// Drift-safe: barrier is collective; each wave drains own reads before it.
// Attention: fragment-layout flash, 64-s iterations (verified round 3).
// Workspace (~167 MiB, liveness-aliased), x2 lives in d_out.
// ---------------------------------------------------------------------------

#define DEV __device__ __forceinline__

typedef unsigned short u16;
typedef __attribute__((ext_vector_type(8))) __bf16 bf16x8;
typedef __attribute__((ext_vector_type(4))) float f32x4;
typedef __attribute__((ext_vector_type(8))) unsigned short u16x8;

typedef __attribute__((address_space(1))) void as1_void;
typedef __attribute__((address_space(3))) void as3_void;

DEV u16 f2b(float f) {                       // f32 -> bf16 RNE (finite inputs)
  unsigned u = __float_as_uint(f);
  u = (u + 0x7fffu + ((u >> 16) & 1u)) >> 16;
  return (u16)u;
}
DEV float b2f(u16 h) { return __uint_as_float(((unsigned)h) << 16); }

DEV f32x4 mfma16(bf16x8 a, bf16x8 b, f32x4 c) {
  return __builtin_amdgcn_mfma_f32_16x16x32_bf16(a, b, c, 0, 0, 0);
}

// async global->LDS, 16B per lane, dest = uniform base + lane*16
DEV void gload16(const void* g, void* l) {
  __builtin_amdgcn_global_load_lds((as1_void*)(unsigned long long)g,
                                   (as3_void*)(unsigned long long)l,
                                   16u, 0, 0u);
}

#define EPI_BF16 0
#define EPI_RELU 1
#define EPI_RES 2
#define EPI_SPLIT 3
#define EPI_QKFRAG 4
#define EPI_VFRAG 5

// ---------------------------------------------------------------------------
// GEMM v3: C[M,N] = A[M,K]*Bt[N,K]^T + bias. BM=256, BK=64, 8 waves.
// Superphase schedule per iteration u (buf cur=u&1):
//   kh0: read A(cur,0) all MF + B(cur,0); stage (u+1).kh1 -> (cur^1,1);
//        MFMA; lgkm0; vmcnt(NW); barrier   [(cur,1) now visible]
//   kh1: read A(cur,1) + B(cur,1); stage (u+2).kh0 -> (cur,0);
//        MFMA; lgkm0; vmcnt(NW); barrier   [(cur^1,0) now visible]
// NW = 2*(LA+LB). FIFO accounting: at kh0's wait, outstanding = u-1.kh1 +
// u.kh0 stages = NW -> everything staged through u-1.kh0 (incl (cur,1))
// complete. Tail stages clamp kt; targets are dead regions.
// ---------------------------------------------------------------------------
template <int BN, int EPI>
__global__ __launch_bounds__(512, 2) void gemm256(
    const u16* __restrict__ A, int lda, int kdup, const u16* __restrict__ Bt,
    const float* __restrict__ bias, const float* __restrict__ res,
    void* __restrict__ Cout, void* __restrict__ Cout2, int ldc, int N, int K) {
  constexpr int MPW = (BN == 256) ? 128 : 64;  // per-wave m rows
  constexpr int MF = MPW / 16;                 // m-frags per wave (8 or 4)
  constexpr int LA = 2;                        // A gloads/thread/superphase
  constexpr int LB = BN / 128;                 // B gloads/thread/superphase
  constexpr int NWAIT = 2 * (LA + LB);         // counted vmcnt
  constexpr int ASZ = 256 * 64;                // bytes per (buf,kh) A region
  constexpr int BSZ = BN * 64;
  constexpr int ATOT = 4 * ASZ;
  __shared__ __align__(1024) char lds[4 * ASZ + 4 * BSZ];

  // XCD-contiguous block swizzle (gridDim.x % 8 == 0 by construction)
  const int nwg = (int)gridDim.x;
  const int cpx = nwg >> 3;
  int w = (int)blockIdx.x;
  w = (w & 7) * cpx + (w >> 3);
  const int nbn = N / BN;
  const int bn = w % nbn, bm = w / nbn;

  const int tid = threadIdx.x;
  const int wave = tid >> 6, lane = tid & 63;
  const int l15 = lane & 15, l4 = lane >> 4;
  const int wm = (BN == 256) ? (wave >> 2) : (wave >> 1);
  const int wn = (BN == 256) ? (wave & 3) : (wave & 1);
  const int nk = K >> 6;

  // staging source: dest row-in-16-group = lane>>2, dest chunk = lane&3;
  // source holds chunk (lane&3) ^ ((row>>1)&3)  [same involution as reads]
  const int srow = lane >> 2;
  const int schunk = ((lane & 3) ^ ((srow >> 1) & 3)) << 4;
  const char* Ab = (const char*)A;
  const char* Bb = (const char*)Bt;
  const int arowA = wave * 32 + srow;
  const int arowB = (LB == 2) ? (wave * 32 + srow) : (wave * 16 + srow);

  auto stageA = [&](int buf, int kh, int kt) {
    const int ktA = (kdup && kt >= kdup) ? kt - kdup : kt;
    const char* s =
        Ab + (size_t)(bm * 256 + arowA) * (size_t)(lda * 2) + ktA * 128 +
        kh * 64 + schunk;
    char* d = lds + (((buf << 1) | kh) * ASZ) + wave * 2048;
    gload16(s, d);
    gload16(s + (size_t)16 * (size_t)(lda * 2), d + 1024);
  };
  auto stageB = [&](int buf, int kh, int kt) {
    const char* s = Bb + (size_t)(bn * BN + arowB) * (size_t)(K * 2) +
                    kt * 128 + kh * 64 + schunk;
    char* d = lds + ATOT + (((buf << 1) | kh) * BSZ) + wave * (LB * 1024);
    gload16(s, d);
    if (LB == 2) gload16(s + (size_t)16 * (size_t)(K * 2), d + 1024);
  };

  const f32x4 fz = {0.f, 0.f, 0.f, 0.f};
  f32x4 acc[MF][4];
#pragma unroll
  for (int i = 0; i < MF; ++i)
#pragma unroll
    for (int j = 0; j < 4; ++j) acc[i][j] = fz;

  // prologue: tile0 full + tile1 kh0, in steady-state issue order
  stageA(0, 0, 0);
  stageB(0, 0, 0);
  stageA(0, 1, 0);
  stageB(0, 1, 0);
  {
    const int k1 = (1 < nk) ? 1 : nk - 1;
    stageA(1, 0, k1);
    stageB(1, 0, k1);
  }
  asm volatile("s_waitcnt vmcnt(%0)" ::"i"(NWAIT) : "memory");
  __builtin_amdgcn_s_barrier();

  for (int u = 0; u < nk; ++u) {
    const int cur = u & 1;
    const int kp1 = (u + 1 < nk) ? u + 1 : nk - 1;
    const int kp2 = (u + 2 < nk) ? u + 2 : nk - 1;
#pragma unroll
    for (int kh = 0; kh < 2; ++kh) {
      const char* Ar = lds + (((cur << 1) | kh) * ASZ);
      const char* Br = lds + ATOT + (((cur << 1) | kh) * BSZ);
      bf16x8 bfr[4], af[MF];
#pragma unroll
      for (int ni = 0; ni < 4; ++ni) {
        const int n = wn * 64 + ni * 16 + l15;
        bfr[ni] = *(const bf16x8*)(Br + n * 64 + ((l4 ^ ((n >> 1) & 3)) << 4));
      }
#pragma unroll
      for (int mi = 0; mi < MF; ++mi) {
        const int m = wm * MPW + mi * 16 + l15;
        af[mi] = *(const bf16x8*)(Ar + m * 64 + ((l4 ^ ((m >> 1) & 3)) << 4));
      }
      if (kh == 0) {
        stageA(cur ^ 1, 1, kp1);
        stageB(cur ^ 1, 1, kp1);
      } else {
        stageA(cur, 0, kp2);
        stageB(cur, 0, kp2);
      }
      __builtin_amdgcn_s_setprio(1);
#pragma unroll
      for (int mi = 0; mi < MF; ++mi)
#pragma unroll
        for (int ni = 0; ni < 4; ++ni)
          acc[mi][ni] = mfma16(af[mi], bfr[ni], acc[mi][ni]);
      __builtin_amdgcn_s_setprio(0);
      // WAR guard: this kh's region is re-staged next superphase.
      asm volatile("s_waitcnt lgkmcnt(0)" ::: "memory");
      // visibility: next superphase's region complete for all waves.
      asm volatile("s_waitcnt vmcnt(%0)" ::"i"(NWAIT) : "memory");
      __builtin_amdgcn_s_barrier();
    }
  }
  asm volatile("s_waitcnt vmcnt(0)" ::: "memory");

  // ---- epilogue ----
#pragma unroll
  for (int mf = 0; mf < MF; ++mf) {
#pragma unroll
    for (int ni = 0; ni < 4; ++ni) {
      const int gn = bn * BN + wn * 64 + ni * 16 + l15;
      const float bia = bias[gn];
#pragma unroll
      for (int r = 0; r < 4; ++r) {
        const int gm = bm * 256 + wm * MPW + mf * 16 + l4 * 4 + r;
        float v = acc[mf][ni][r] + bia;
        if (EPI == EPI_BF16) {
          ((u16*)Cout)[(size_t)gm * ldc + gn] = f2b(v);
        } else if (EPI == EPI_RELU) {
          ((u16*)Cout)[(size_t)gm * ldc + gn] = f2b(v > 0.f ? v : 0.f);
        } else if (EPI == EPI_RES) {
          ((float*)Cout)[(size_t)gm * ldc + gn] =
              v + res[(size_t)gm * ldc + gn];
        } else if (EPI == EPI_SPLIT) {  // [hi | lo] planes within row
          u16 hi = f2b(v);
          ((u16*)Cout)[(size_t)gm * ldc + gn] = hi;
          ((u16*)Cout)[(size_t)gm * ldc + N + gn] = f2b(v - b2f(hi));
        } else if (EPI == EPI_QKFRAG) {
          // gm=(b,s); gn<1024: q -> Cout frags; gn>=1024: k -> Cout2.
          const int b = gm >> 9, s = gm & 511;
          const int gs = s >> 4, sr = s & 15;
          const int n = gn & 1023;
          const int h = n >> 6, e = n & 63;
          u16* base = (u16*)((gn >> 10) ? Cout2 : Cout);
          const size_t blk = ((size_t)(b * 16 + h) * 32 + gs) * 4;
          const int idx = ((e >> 3) & 3) * 128 + sr * 8 + (e & 7);
          const u16 hi = f2b(v);
          base[(blk + (e >> 5)) * 512 + idx] = hi;
          base[(blk + 2 + (e >> 5)) * 512 + idx] = f2b(v - b2f(hi));
        } else {  // EPI_VFRAG: B-operand frag for PV
          const int b = gm >> 9, s = gm & 511;
          const int h = gn >> 6, e = gn & 63;
          const size_t blk =
              ((size_t)(b * 16 + h) * 16 + (s >> 5)) * 4 + (e >> 4);
          ((u16*)Cout)[blk * 512 + ((s >> 3) & 3) * 128 + (e & 15) * 8 +
                       (s & 7)] = f2b(v);
        }
      }
    }
  }
}

// ---------------------------------------------------------------------------
// LayerNorm row kernel. SPLIT: out row = [hi(1024) | lo(1024)] (stride 2048).
// ---------------------------------------------------------------------------
template <bool SPLIT>
__global__ __launch_bounds__(256) void lnorm(const float* __restrict__ x,
                                             const float* __restrict__ g,
                                             const float* __restrict__ bt,
                                             u16* __restrict__ out) {
  const int row = blockIdx.x, tid = threadIdx.x;
  const int wave = tid >> 6, lane = tid & 63;
  const float4 v = *(const float4*)(x + (size_t)row * 1024 + tid * 4);
  float xv[4] = {v.x, v.y, v.z, v.w};
  float s = xv[0] + xv[1] + xv[2] + xv[3];
  float s2 = xv[0] * xv[0] + xv[1] * xv[1] + xv[2] * xv[2] + xv[3] * xv[3];
  for (int off = 32; off; off >>= 1) {
    s += __shfl_down(s, off);
    s2 += __shfl_down(s2, off);
  }
  __shared__ float red[8];
  if (lane == 0) {
    red[wave] = s;
    red[4 + wave] = s2;
  }
  __syncthreads();
  const float ts = red[0] + red[1] + red[2] + red[3];
  const float ts2 = red[4] + red[5] + red[6] + red[7];
  const float mean = ts * (1.f / 1024.f);
  const float var = ts2 * (1.f / 1024.f) - mean * mean;
  const float rstd = rsqrtf(var + 1e-5f);
#pragma unroll
  for (int j = 0; j < 4; ++j) {
    const int col = tid * 4 + j;
    const float y = (xv[j] - mean) * rstd * g[col] + bt[col];
    const u16 hi = f2b(y);
    if (SPLIT) {
      out[(size_t)row * 2048 + col] = hi;
      out[(size_t)row * 2048 + 1024 + col] = f2b(y - b2f(hi));
    } else {
      out[(size_t)row * 1024 + col] = hi;
    }
  }
}

// ---------------------------------------------------------------------------
// Weight transpose f32[K][cols] -> bf16 out[n][k] (row stride ors).
// SPLIT: out row = [hi | lo | hi] at offsets {0, Koff, 2*Koff}.
// grid: (cols/64, K/64, batch)
// ---------------------------------------------------------------------------
template <bool SPLIT>
__global__ __launch_bounds__(256) void wtrans(const float* __restrict__ in,
                                              int kstride, long ibs,
                                              u16* __restrict__ out, int ors,
                                              long obs, int Koff) {
  in += (size_t)blockIdx.z * ibs;
  out += (size_t)blockIdx.z * obs;
  const int n0 = blockIdx.x * 64, k0 = blockIdx.y * 64;
  const int tid = threadIdx.x;
  __shared__ float tt[64][65];
  const int r = tid >> 4, c4 = (tid & 15) * 4;
#pragma unroll
  for (int p = 0; p < 4; ++p) {
    const int rr = r + p * 16;
    const float4 vv =
        *(const float4*)(in + (size_t)(k0 + rr) * kstride + n0 + c4);
    tt[rr][c4] = vv.x;
    tt[rr][c4 + 1] = vv.y;
    tt[rr][c4 + 2] = vv.z;
    tt[rr][c4 + 3] = vv.w;
  }
  __syncthreads();
  const int nl = tid >> 2, kc = (tid & 3) * 16;
  u16 hi[16], lo[16];
#pragma unroll
  for (int j = 0; j < 16; ++j) {
    const float w = tt[kc + j][nl];
    hi[j] = f2b(w);
    if (SPLIT) lo[j] = f2b(w - b2f(hi[j]));
  }
  u16* orow = out + (size_t)(n0 + nl) * ors + k0 + kc;
  u16x8 a, b;
#pragma unroll
  for (int j = 0; j < 8; ++j) {
    a[j] = hi[j];
    b[j] = hi[8 + j];
  }
  *(u16x8*)(orow) = a;
  *(u16x8*)(orow + 8) = b;
  if (SPLIT) {
    *(u16x8*)(orow + 2 * Koff) = a;
    *(u16x8*)(orow + 2 * Koff + 8) = b;
    u16x8 c, d;
#pragma unroll
    for (int j = 0; j < 8; ++j) {
      c[j] = lo[j];
      d[j] = lo[8 + j];
    }
    *(u16x8*)(orow + Koff) = c;
    *(u16x8*)(orow + Koff + 8) = d;
  }
}

__global__ void biascat(const float* __restrict__ bq,
                        const float* __restrict__ bk, float* __restrict__ o) {
  const int i = blockIdx.x * 256 + threadIdx.x;  // 2048 total
  o[i] = (i < 1024) ? bq[i] : bk[i - 1024];
}

__global__ void fillconst(float* __restrict__ p, float v, int n) {
  const int i = blockIdx.x * 256 + threadIdx.x;
  if (i < n) p[i] = v;
}

// ---------------------------------------------------------------------------
// Flash attention (fragment layouts, 64-s iterations) — verified round 3.
// ---------------------------------------------------------------------------
__global__ __launch_bounds__(256) void attn_fwd(const u16* __restrict__ qf,
                                                const u16* __restrict__ kf,
                                                const u16* __restrict__ vf,
                                                u16* __restrict__ o) {
  const int bh = blockIdx.y;
  const int b = bh >> 4, h = bh & 15;
  const int xt = 7 - (int)blockIdx.x;  // heavy tiles dispatch first
  const int tid = threadIdx.x, wave = tid >> 6, lane = tid & 63;
  const int l15 = lane & 15, l4 = lane >> 4;
  const int gt = xt * 4 + wave;  // 16-row t-group, 0..31
  const int tw = gt * 16;
  __shared__ u16 Pl[4][1024];  // per-wave 16x64 bf16 P, 128B rows, swizzled

  const u16* kfb = kf + ((size_t)(bh * 32 + gt) * 4) * 512 + lane * 8;
  const bf16x8 kh0 = *(const bf16x8*)(kfb);
  const bf16x8 kh1 = *(const bf16x8*)(kfb + 512);
  const bf16x8 kl0 = *(const bf16x8*)(kfb + 1024);
  const bf16x8 kl1 = *(const bf16x8*)(kfb + 1536);

  const f32x4 fz = {0.f, 0.f, 0.f, 0.f};
  f32x4 oacc[4] = {fz, fz, fz, fz};
  float mrow[4] = {-1e30f, -1e30f, -1e30f, -1e30f};
  float lrow[4] = {0.f, 0.f, 0.f, 0.f};
  const u16* qfb = qf + (size_t)bh * 32 * 2048 + lane * 8;
  const u16* vfb = vf + (size_t)bh * 16 * 2048 + lane * 8;
  const int niter = (tw + 79) >> 6;

  for (int it = 0; it < niter; ++it) {
    const int s0 = it * 64;
    bf16x8 qh[4][2], ql[4][2];
#pragma unroll
    for (int scb = 0; scb < 4; ++scb) {
      const u16* qp = qfb + (size_t)((s0 >> 4) + scb) * 2048;
      qh[scb][0] = *(const bf16x8*)(qp);
      qh[scb][1] = *(const bf16x8*)(qp + 512);
      ql[scb][0] = *(const bf16x8*)(qp + 1024);
      ql[scb][1] = *(const bf16x8*)(qp + 1536);
    }
    bf16x8 vv[2][4];
#pragma unroll
    for (int h2 = 0; h2 < 2; ++h2) {
      const u16* vp = vfb + (size_t)((s0 >> 5) + h2) * 2048;
#pragma unroll
      for (int eF = 0; eF < 4; ++eF)
        vv[h2][eF] = *(const bf16x8*)(vp + eF * 512);
    }
    f32x4 sf[4];
#pragma unroll
    for (int scb = 0; scb < 4; ++scb) {
      f32x4 z = fz;
      z = mfma16(kh0, qh[scb][0], z);
      z = mfma16(kh1, qh[scb][1], z);
      z = mfma16(kh0, ql[scb][0], z);
      z = mfma16(kh1, ql[scb][1], z);
      z = mfma16(kl0, qh[scb][0], z);
      z = mfma16(kl1, qh[scb][1], z);
      sf[scb] = z;
    }
    if (s0 + 63 > tw) {
#pragma unroll
      for (int scb = 0; scb < 4; ++scb)
#pragma unroll
        for (int r = 0; r < 4; ++r) {
          const int s = s0 + scb * 16 + l15, t = tw + l4 * 4 + r;
          if (s > t) sf[scb][r] = -1e30f;
        }
    }
    float scl[4];
#pragma unroll
    for (int r = 0; r < 4; ++r) {
      float v = fmaxf(fmaxf(sf[0][r], sf[1][r]), fmaxf(sf[2][r], sf[3][r]));
      v = fmaxf(v, __shfl_xor(v, 1));
      v = fmaxf(v, __shfl_xor(v, 2));
      v = fmaxf(v, __shfl_xor(v, 4));
      v = fmaxf(v, __shfl_xor(v, 8));
      const float mn = fmaxf(mrow[r], v);
      scl[r] = __expf(mrow[r] - mn);
      mrow[r] = mn;
    }
    float ps[4] = {0.f, 0.f, 0.f, 0.f};
#pragma unroll
    for (int scb = 0; scb < 4; ++scb)
#pragma unroll
      for (int r = 0; r < 4; ++r) {
        const float p = __expf(sf[scb][r] - mrow[r]);
        sf[scb][r] = p;
        ps[r] += p;
      }
#pragma unroll
    for (int r = 0; r < 4; ++r) {
      float v = ps[r];
      v += __shfl_xor(v, 1);
      v += __shfl_xor(v, 2);
      v += __shfl_xor(v, 4);
      v += __shfl_xor(v, 8);
      lrow[r] = lrow[r] * scl[r] + v;
      oacc[0][r] *= scl[r];
      oacc[1][r] *= scl[r];
      oacc[2][r] *= scl[r];
      oacc[3][r] *= scl[r];
    }
#pragma unroll
    for (int scb = 0; scb < 4; ++scb)
#pragma unroll
      for (int r = 0; r < 4; ++r) {
        const int trow = l4 * 4 + r, scol = scb * 16 + l15;
        const int byte = trow * 128 + ((scol * 2) ^ ((trow & 7) << 4));
        *(u16*)((char*)&Pl[wave][0] + byte) = f2b(sf[scb][r]);
      }
#pragma unroll
    for (int h2 = 0; h2 < 2; ++h2) {
      const bf16x8 pf = *(const bf16x8*)((const char*)&Pl[wave][0] +
                                         l15 * 128 +
                                         (((h2 * 4 + l4) ^ (l15 & 7)) << 4));
#pragma unroll
      for (int eF = 0; eF < 4; ++eF)
        oacc[eF] = mfma16(pf, vv[h2][eF], oacc[eF]);
    }
  }
#pragma unroll
  for (int eF = 0; eF < 4; ++eF)
#pragma unroll
    for (int r = 0; r < 4; ++r) {
      const int t = tw + l4 * 4 + r;
      const float val = oacc[eF][r] / lrow[r];
      o[(size_t)(b * 512 + t) * 1024 + h * 64 + eF * 16 + l15] = f2b(val);
    }
}

// ---------------------------------------------------------------------------
extern "C" void kernel_launch(void* const* d_in, const int* in_sizes, int n_in,
                              void* d_out, int out_size, void* d_ws,
                              size_t ws_size, hipStream_t stream) {
  const float* x = (const float*)d_in[0];
  const float* ga = (const float*)d_in[1];
  const float* ba = (const float*)d_in[2];
  const float* Win = (const float*)d_in[3];
  const float* bin = (const float*)d_in[4];
  const float* Wk = (const float*)d_in[5];
  const float* bk = (const float*)d_in[6];
  const float* Wq = (const float*)d_in[7];
  const float* bq = (const float*)d_in[8];
  const float* Wv = (const float*)d_in[9];
  const float* bv = (const float*)d_in[10];
  const float* Wout = (const float*)d_in[11];
  const float* bout = (const float*)d_in[12];
  const float* gf = (const float*)d_in[13];
  const float* bf_ = (const float*)d_in[14];
  const float* W1 = (const float*)d_in[15];
  const float* b1 = (const float*)d_in[16];
  const float* W2 = (const float*)d_in[17];
  const float* b2 = (const float*)d_in[18];
  float* out = (float*)d_out;

  char* ws = (char*)d_ws;
  size_t off = 0;
  auto alloc = [&](size_t bytes) {
    char* p = ws + off;
    off += (bytes + 255) & ~(size_t)255;
    return p;
  };
  u16* WinT = (u16*)alloc((size_t)1024 * 3072 * 2);  // [n][hi|lo|hi]
  u16* WqkT = (u16*)alloc((size_t)2048 * 3072 * 2);  // rows 0..1023 q, rest k
  u16* WvT = (u16*)alloc((size_t)1024 * 1024 * 2);
  u16* WoutT = (u16*)alloc((size_t)1024 * 1024 * 2);
  u16* W1T = (u16*)alloc((size_t)4096 * 1024 * 2);
  u16* W2T = (u16*)alloc((size_t)1024 * 4096 * 2);
  float* bqk = (float*)alloc(2048 * 4);
  char* R1 = alloc((size_t)8192 * 2048 * 2);  // ln1 -> vf
  char* R2 = alloc((size_t)8192 * 2048 * 2);  // hb  -> ob, ln2
  char* QK = alloc((size_t)2 * 256 * 32 * 4 * 1024);  // qf+kf (64MB) -> ffn1
  const size_t need = off;                            // ~167 MiB

  if (need > ws_size) {  // diagnostic sentinel: ws too small -> absmax ~12345
    fillconst<<<(out_size + 255) / 256, 256, 0, stream>>>(out, 12345.0f,
                                                          out_size);
    return;
  }

  u16* ln1 = (u16*)R1;                              // 32 MiB
  u16* vfb = (u16*)R1;                              // 16 MiB, after ln1 dead
  u16* hb = (u16*)R2;                               // 32 MiB
  u16* ob = (u16*)R2;                               // after hb dead
  u16* ln2 = (u16*)(R2 + (size_t)8192 * 1024 * 2);  // second 16 MiB
  u16* qfb = (u16*)QK;                              // 32 MiB
  u16* kfb = (u16*)(QK + (size_t)256 * 32 * 4 * 1024);  // 32 MiB
  u16* ffn1 = (u16*)QK;                             // after attn, qf/kf dead
  float* x2 = out;                                  // d_out doubles as x2

  // ---- weight prep (bf16 [+split] transposes) ----
  wtrans<true><<<dim3(16, 16, 1), 256, 0, stream>>>(Win, 1024, 0, WinT, 3072,
                                                    0, 1024);
  wtrans<true><<<dim3(1, 16, 16), 256, 0, stream>>>(Wq, 64, 65536, WqkT, 3072,
                                                    (long)64 * 3072, 1024);
  wtrans<true><<<dim3(1, 16, 16), 256, 0, stream>>>(
      Wk, 64, 65536, WqkT + (size_t)1024 * 3072, 3072, (long)64 * 3072, 1024);
  wtrans<false><<<dim3(1, 16, 16), 256, 0, stream>>>(Wv, 64, 65536, WvT, 1024,
                                                     (long)64 * 1024, 0);
  wtrans<false><<<dim3(16, 16, 1), 256, 0, stream>>>(Wout, 1024, 0, WoutT,
                                                     1024, 0, 0);
  wtrans<false><<<dim3(64, 16, 1), 256, 0, stream>>>(W1, 4096, 0, W1T, 1024, 0,
                                                     0);
  wtrans<false><<<dim3(16, 64, 1), 256, 0, stream>>>(W2, 1024, 0, W2T, 4096, 0,
                                                     0);
  biascat<<<8, 256, 0, stream>>>(bq, bk, bqk);

  // ---- pipeline ----
  lnorm<true><<<8192, 256, 0, stream>>>(x, ga, ba, ln1);
  // h = ln1 @ Win + bin  (split-K 3072, split output)
  gemm256<128, EPI_SPLIT><<<256, 512, 0, stream>>>(
      ln1, 2048, 16, WinT, bin, nullptr, hb, nullptr, 2048, 1024, 3072);
  // [q|k] = h @ [Wq|Wk]  (split-K, fragment-layout split output)
  gemm256<256, EPI_QKFRAG><<<256, 512, 0, stream>>>(
      hb, 2048, 16, WqkT, bqk, nullptr, qfb, kfb, 0, 2048, 3072);
  // v = h_hi @ Wv + bv  (fragment layout, overwrites ln1 region: dead)
  gemm256<128, EPI_VFRAG><<<256, 512, 0, stream>>>(
      hb, 2048, 0, WvT, bv, nullptr, vfb, nullptr, 0, 1024, 1024);
  attn_fwd<<<dim3(8, 256), 256, 0, stream>>>(qfb, kfb, vfb, ob);
  // x2 = o @ Wout + bout + x   (x2 == d_out)
  gemm256<128, EPI_RES><<<256, 512, 0, stream>>>(
      ob, 1024, 0, WoutT, bout, x, x2, nullptr, 1024, 1024, 1024);
  lnorm<false><<<8192, 256, 0, stream>>>(x2, gf, bf_, ln2);
  // ffn1 = relu(ln2 @ W1 + b1)   (overwrites qf/kf region: dead)
  gemm256<256, EPI_RELU><<<512, 512, 0, stream>>>(
      ln2, 1024, 0, W1T, b1, nullptr, ffn1, nullptr, 4096, 4096, 1024);
  // out = ffn1 @ W2 + b2 + x2   (res == Cout == d_out, element-wise safe)
  gemm256<128, EPI_RES><<<256, 512, 0, stream>>>(
      ffn1, 4096, 0, W2T, b2, x2, out, nullptr, 1024, 1024, 4096);
}